// Round 7
// baseline (476.709 us; speedup 1.0000x reference)
//
#include <hip/hip_runtime.h>
#include <hip/hip_bf16.h>
#include <stdint.h>

// y[b,s,o] = x[b,s,:] . (wq[o,:]*scale) + bias[o]
// i8 GEMM: C[M,N] = Xq[M,K](i8, per-row scale) @ Wq[N,K](i8 exact)^T
// M=8192 N=11008 K=4096. i32 accum exact (4096*127^2 < 2^31).
//
// R7: occupancy play. 256x128 block, 512 thr (8 waves, 4Mx2N), per-wave
// 64x64 out: acc[4][4]=64 AGPR + ~60 arch VGPR -> <=128 total -> 4 waves/SIMD
// (vs 2 in ALL prior rounds). Ring-3 x 24KB = 72KB LDS -> 2 blocks/CU,
// 16 waves/CU, independent barrier domains. The per-wave ds_read->MFMA
// serial chain is hidden by TLP instead of intra-wave pipelining.
// Ledger (3 stage calls/iter): barrier1=WAR -> stage(t+2) -> read frags(t)
// -> MFMA -> vmcnt(3) [t+1 landed, t+2 in flight] -> barrier2 publish t+1.
// Swizzle byte-identical to R0.
#define M_TOT 8192
#define N_TOT 11008
#define K_TOT 4096
#define BM 256
#define BN 128
#define BK 64             // i8 K-tile depth (64 B rows)
#define KT (K_TOT / BK)   // 64
#define NTM (M_TOT / BM)  // 32
#define NTN (N_TOT / BN)  // 86
#define NBLK (NTM * NTN)  // 2752 (%8==0)
#define BUFB 24576        // one K-tile: A 16KB + B 8KB (i8)
#define LDSB (3 * BUFB)   // 72 KB, 3-deep ring -> 2 blocks/CU
#define ROWB K_TOT        // 4096 B per global i8 row

typedef int i32x4 __attribute__((ext_vector_type(4)));

// ---- x row-quantization: one block per row, absmax -> i8 + per-row scale ----
__global__ __launch_bounds__(256) void quant_x_kernel(const float* __restrict__ x,
                                                      char* __restrict__ xq,
                                                      float* __restrict__ sr) {
  __shared__ float red[4];
  const int r = blockIdx.x;
  const int t = threadIdx.x;
  const float4* px = (const float4*)(x + (long)r * K_TOT) + t * 4;
  float4 v0 = px[0], v1 = px[1], v2 = px[2], v3 = px[3];
  float f[16] = {v0.x, v0.y, v0.z, v0.w, v1.x, v1.y, v1.z, v1.w,
                 v2.x, v2.y, v2.z, v2.w, v3.x, v3.y, v3.z, v3.w};
  float m = 0.f;
#pragma unroll
  for (int i = 0; i < 16; ++i) m = fmaxf(m, fabsf(f[i]));
#pragma unroll
  for (int off = 1; off < 64; off <<= 1) m = fmaxf(m, __shfl_xor(m, off));
  if ((t & 63) == 0) red[t >> 6] = m;
  __syncthreads();
  m = fmaxf(fmaxf(red[0], red[1]), fmaxf(red[2], red[3]));
  m = fmaxf(m, 1e-20f);
  const float inv = 127.0f / m;
  int q[16];
#pragma unroll
  for (int i = 0; i < 16; ++i) q[i] = __float2int_rn(f[i] * inv);
  int4 o;
  o.x = (q[0] & 255) | ((q[1] & 255) << 8) | ((q[2] & 255) << 16) | (q[3] << 24);
  o.y = (q[4] & 255) | ((q[5] & 255) << 8) | ((q[6] & 255) << 16) | (q[7] << 24);
  o.z = (q[8] & 255) | ((q[9] & 255) << 8) | ((q[10] & 255) << 16) | (q[11] << 24);
  o.w = (q[12] & 255) | ((q[13] & 255) << 8) | ((q[14] & 255) << 16) | (q[15] << 24);
  ((int4*)(xq + (long)r * K_TOT))[t] = o;
  if (t == 0) sr[r] = m / 127.0f;
}

// ---- w pack: int32 codes 0..126 -> i8 (exact), 16/thread ----
__global__ __launch_bounds__(256) void cvt_w8_kernel(const int* __restrict__ w,
                                                     char* __restrict__ wq,
                                                     long n16) {
  long i = (long)blockIdx.x * 256 + threadIdx.x;
  if (i >= n16) return;
  const int4* p = (const int4*)w + i * 4;
  int4 a = p[0], b = p[1], c = p[2], d = p[3];
  int4 o;
  o.x = (a.x & 255) | ((a.y & 255) << 8) | ((a.z & 255) << 16) | (a.w << 24);
  o.y = (b.x & 255) | ((b.y & 255) << 8) | ((b.z & 255) << 16) | (b.w << 24);
  o.z = (c.x & 255) | ((c.y & 255) << 8) | ((c.z & 255) << 16) | (c.w << 24);
  o.w = (d.x & 255) | ((d.y & 255) << 8) | ((d.z & 255) << 16) | (d.w << 24);
  ((int4*)wq)[i] = o;
}

__device__ __forceinline__ void gload_lds16(const void* g, void* l) {
  __builtin_amdgcn_global_load_lds((const __attribute__((address_space(1))) void*)g,
                                   (__attribute__((address_space(3))) void*)l,
                                   16, 0, 0);
}

// 256x128 tile, BK=64 i8, 8 waves (4M x 2N), per-wave 64x64 out, acc[4][4].
// 64B logical rows paired into 128B phys rows, XOR ((pr&7)<<4) swizzle.
// One stage call = 512 thr x 16B = 8KB: A needs 2 calls, B 1 call per tile.
__global__ __launch_bounds__(512, 4) void gemm256_i8_kernel(
    const unsigned char* __restrict__ A,   // [M,K] i8
    const unsigned char* __restrict__ Bw,  // [N,K] i8
    const float* __restrict__ sr,          // [M] per-row x scale
    const float* __restrict__ scale,
    const float* __restrict__ bias,
    float* __restrict__ C) {
  extern __shared__ char lds[];
  const int tid = threadIdx.x;
  const int lane = tid & 63;
  const int wid = tid >> 6;  // 0..7
  const int wm = wid >> 1;   // 0..3, rows wm*64
  const int wn = wid & 1;    // 0..1, cols wn*64
  const int l16 = lane & 15;
  const int kh = lane >> 4;  // 0..3

  // XCD-aware bijective swizzle (2752 % 8 == 0)
  const int bid = blockIdx.x;
  const int wg = (bid & 7) * (NBLK / 8) + (bid >> 3);
  const int tm = wg / NTN, tn = wg % NTN;
  const long m0 = (long)tm * BM, n0 = (long)tn * BN;

  // ---- staging source (pre-swizzled global addr; LDS dest linear) ----
  // One call: 512 threads x 16B = 8KB = 64 phys rows (128 logical rows).
  const int prl = tid >> 3;                          // phys row within 8KB call
  const int cp = ((tid & 7) * 16) ^ ((prl & 7) << 4);
  const int hsel = cp >> 6;
  const int colb = cp & 63;
  const char* gA = (const char*)A + (m0 + 2 * prl + hsel) * (long)ROWB + colb;
  const char* gB = (const char*)Bw + (n0 + 2 * prl + hsel) * (long)ROWB + colb;
  const int ldsT = tid * 16;

  // ---- LDS read addressing (swizzled; logical row r -> phys r>>1, half r&1) ----
  const int inner = (((lane & 1) << 6) | (kh << 4)) ^ (((l16 >> 1) & 7) << 4);
  const int aB = (wm * 32 + (l16 >> 1)) * 128 + inner;          // + mi*1024
  const int bB = 16384 + (wn * 32 + (l16 >> 1)) * 128 + inner;  // + ni*1024

  i32x4 acc[4][4] = {};
  i32x4 af[4], bf[4];

  // Stage calls for slot S (compile-time): A chunks q=0,1; B one call.
#define STG_A(S, q, kb) gload_lds16(gA + (q) * (128L * ROWB) + (kb), \
                                    lds + (S) * BUFB + (q) * 8192 + ldsT)
#define STG_B(S, kb)    gload_lds16(gB + (kb), \
                                    lds + (S) * BUFB + 16384 + ldsT)

  // ---- prologue: stage tiles 0 (slot 0), 1 (slot 1); publish tile 0 ----
  STG_A(0, 0, 0); STG_A(0, 1, 0); STG_B(0, 0);
  STG_A(1, 0, 64); STG_A(1, 1, 64); STG_B(1, 64);
  asm volatile("s_waitcnt vmcnt(3)" ::: "memory");  // tile 0 landed (this wave)
  asm volatile("s_barrier" ::: "memory");           // publish tile 0

  int t = 0;
  long ktB = 128;  // stage byte offset for tile t+2 at group position P=0

  // ITER(S = slot of t, SS = slot of t+2, KOFF).
#define ITER(S, SS, KOFF)                                                     \
  {                                                                           \
    asm volatile("s_barrier" ::: "memory");  /* WAR: slot SS reads done */    \
    if (t < KT - 2) {                                                         \
      STG_A(SS, 0, ktB + (KOFF)); STG_A(SS, 1, ktB + (KOFF));                 \
      STG_B(SS, ktB + (KOFF));                                                \
    }                                                                         \
    _Pragma("unroll")                                                         \
    for (int i = 0; i < 4; ++i) {                                             \
      af[i] = *(const i32x4*)(lds + (S) * BUFB + aB + i * 1024);              \
      bf[i] = *(const i32x4*)(lds + (S) * BUFB + bB + i * 1024);              \
    }                                                                         \
    __builtin_amdgcn_sched_barrier(0);                                        \
    __builtin_amdgcn_s_setprio(1);                                            \
    _Pragma("unroll")                                                         \
    for (int mi = 0; mi < 4; ++mi)                                            \
      _Pragma("unroll")                                                       \
      for (int ni = 0; ni < 4; ++ni)                                          \
        acc[mi][ni] = __builtin_amdgcn_mfma_i32_16x16x64_i8(af[mi], bf[ni], acc[mi][ni], 0, 0, 0); \
    __builtin_amdgcn_s_setprio(0);                                            \
    __builtin_amdgcn_sched_barrier(0);                                        \
    if (t < KT - 2) asm volatile("s_waitcnt vmcnt(3)" ::: "memory");          \
    else            asm volatile("s_waitcnt vmcnt(0)" ::: "memory");          \
    asm volatile("s_barrier" ::: "memory");  /* publish tile t+1 */           \
    ++t;                                                                      \
  }

  // 21 groups of 3 (t=0..62), then tail t=63 (slot 0).
  for (int tt = 0; tt < 21; ++tt) {
    ITER(0, 2, 0);
    ITER(1, 0, 64);
    ITER(2, 1, 128);
    ktB += 192;
  }
  // t == 63: tile 63 already published by iter 62's barrier2.
  {
#pragma unroll
    for (int i = 0; i < 4; ++i) {
      af[i] = *(const i32x4*)(lds + 0 * BUFB + aB + i * 1024);
      bf[i] = *(const i32x4*)(lds + 0 * BUFB + bB + i * 1024);
    }
    __builtin_amdgcn_s_setprio(1);
#pragma unroll
    for (int mi = 0; mi < 4; ++mi)
#pragma unroll
      for (int ni = 0; ni < 4; ++ni)
        acc[mi][ni] = __builtin_amdgcn_mfma_i32_16x16x64_i8(af[mi], bf[ni], acc[mi][ni], 0, 0, 0);
    __builtin_amdgcn_s_setprio(0);
  }
#undef ITER
#undef STG_A
#undef STG_B

  // ---- epilogue: y = i32acc * (sr[row]*s) + bias ----
  const float sw = scale[0];
  float bv[4];
#pragma unroll
  for (int ni = 0; ni < 4; ++ni) bv[ni] = bias[n0 + wn * 64 + ni * 16 + l16];
#pragma unroll
  for (int mi = 0; mi < 4; ++mi) {
#pragma unroll
    for (int j = 0; j < 4; ++j) {
      const long row = m0 + wm * 64 + mi * 16 + kh * 4 + j;
      const float rsw = sr[row] * sw;
#pragma unroll
      for (int ni = 0; ni < 4; ++ni) {
        const long col = n0 + wn * 64 + ni * 16 + l16;
        C[row * N_TOT + col] = (float)acc[mi][ni][j] * rsw + bv[ni];
      }
    }
  }
}

// ---- fallback (shouldn't trigger) ----
__global__ __launch_bounds__(256) void naive_kernel(const float* __restrict__ x,
                                                    const int* __restrict__ wq,
                                                    const float* __restrict__ scale,
                                                    const float* __restrict__ bias,
                                                    float* __restrict__ out) {
  long idx = (long)blockIdx.x * 256 + threadIdx.x;
  if (idx >= (long)M_TOT * N_TOT) return;
  long m = idx / N_TOT, n = idx % N_TOT;
  const float* xr = x + m * (long)K_TOT;
  const int* wr = wq + n * (long)K_TOT;
  float acc = 0.f;
  for (int k = 0; k < K_TOT; ++k) acc += xr[k] * (float)wr[k];
  out[idx] = acc * scale[0] + bias[n];
}

extern "C" void kernel_launch(void* const* d_in, const int* in_sizes, int n_in,
                              void* d_out, int out_size, void* d_ws, size_t ws_size,
                              hipStream_t stream) {
  const float* x = (const float*)d_in[0];
  const int* wq = (const int*)d_in[1];
  const float* scale = (const float*)d_in[2];
  const float* bias = (const float*)d_in[3];
  float* out = (float*)d_out;

  const long xe = (long)M_TOT * K_TOT;  // 33,554,432 B (i8)
  const long we = (long)N_TOT * K_TOT;  // 45,088,768 B (i8)
  const size_t need = (size_t)xe + we + M_TOT * sizeof(float);

  if (ws_size >= need) {
    char* xq = (char*)d_ws;
    char* wb = xq + xe;
    float* sr = (float*)(wb + we);
    quant_x_kernel<<<M_TOT, 256, 0, stream>>>(x, xq, sr);
    cvt_w8_kernel<<<(int)((we / 16 + 255) / 256), 256, 0, stream>>>(wq, wb, we / 16);
    (void)hipFuncSetAttribute((const void*)gemm256_i8_kernel,
                              hipFuncAttributeMaxDynamicSharedMemorySize, LDSB);
    gemm256_i8_kernel<<<NBLK, 512, LDSB, stream>>>((const unsigned char*)xq,
                                                   (const unsigned char*)wb,
                                                   sr, scale, bias, out);
  } else {
    long total = (long)M_TOT * N_TOT;
    naive_kernel<<<(int)((total + 255) / 256), 256, 0, stream>>>(x, wq, scale, bias, out);
  }
}

// Round 8
// 456.660 us; speedup vs baseline: 1.0439x; 1.0439x over previous
//
#include <hip/hip_runtime.h>
#include <hip/hip_bf16.h>
#include <stdint.h>

// y[b,s,o] = x[b,s,:] . (wq[o,:]*scale) + bias[o]
// i8 GEMM: C[M,N] = Xq[M,K](i8, per-row scale) @ Wq[N,K](i8 exact)^T
// M=8192 N=11008 K=4096. i32 accum exact (4096*127^2 < 2^31).
//
// R8: R5 (best, 390us GEMM) with ALL intra-iter scheduling pins removed:
// no sched_barrier(0), no s_setprio. Barriers + counted vmcnt (memory
// clobber) still order LDS/staging; the compiler is free to interleave
// ds_reads with MFMAs and emit fine-grained lgkmcnt (m97-style pipelining;
// m141 showed order-pinning costs ~40% vs free compilation).
#define M_TOT 8192
#define N_TOT 11008
#define K_TOT 4096
#define BM 256
#define BN 256
#define BK 64             // i8 K-tile depth (64 B rows)
#define KT (K_TOT / BK)   // 64
#define NTM (M_TOT / BM)  // 32
#define NTN (N_TOT / BN)  // 43
#define NBLK (NTM * NTN)  // 1376 (%8==0)
#define BUFB 32768        // one K-tile: A 16KB + B 16KB (i8)
#define LDSB (4 * BUFB)   // 128 KB, 4-deep ring
#define ROWB K_TOT        // 4096 B per global i8 row

typedef int i32x4 __attribute__((ext_vector_type(4)));

// ---- x row-quantization: one block per row, absmax -> i8 + per-row scale ----
__global__ __launch_bounds__(256) void quant_x_kernel(const float* __restrict__ x,
                                                      char* __restrict__ xq,
                                                      float* __restrict__ sr) {
  __shared__ float red[4];
  const int r = blockIdx.x;
  const int t = threadIdx.x;
  const float4* px = (const float4*)(x + (long)r * K_TOT) + t * 4;
  float4 v0 = px[0], v1 = px[1], v2 = px[2], v3 = px[3];
  float f[16] = {v0.x, v0.y, v0.z, v0.w, v1.x, v1.y, v1.z, v1.w,
                 v2.x, v2.y, v2.z, v2.w, v3.x, v3.y, v3.z, v3.w};
  float m = 0.f;
#pragma unroll
  for (int i = 0; i < 16; ++i) m = fmaxf(m, fabsf(f[i]));
#pragma unroll
  for (int off = 1; off < 64; off <<= 1) m = fmaxf(m, __shfl_xor(m, off));
  if ((t & 63) == 0) red[t >> 6] = m;
  __syncthreads();
  m = fmaxf(fmaxf(red[0], red[1]), fmaxf(red[2], red[3]));
  m = fmaxf(m, 1e-20f);
  const float inv = 127.0f / m;
  int q[16];
#pragma unroll
  for (int i = 0; i < 16; ++i) q[i] = __float2int_rn(f[i] * inv);
  int4 o;
  o.x = (q[0] & 255) | ((q[1] & 255) << 8) | ((q[2] & 255) << 16) | (q[3] << 24);
  o.y = (q[4] & 255) | ((q[5] & 255) << 8) | ((q[6] & 255) << 16) | (q[7] << 24);
  o.z = (q[8] & 255) | ((q[9] & 255) << 8) | ((q[10] & 255) << 16) | (q[11] << 24);
  o.w = (q[12] & 255) | ((q[13] & 255) << 8) | ((q[14] & 255) << 16) | (q[15] << 24);
  ((int4*)(xq + (long)r * K_TOT))[t] = o;
  if (t == 0) sr[r] = m / 127.0f;
}

// ---- w pack: int32 codes 0..126 -> i8 (exact), 16/thread ----
__global__ __launch_bounds__(256) void cvt_w8_kernel(const int* __restrict__ w,
                                                     char* __restrict__ wq,
                                                     long n16) {
  long i = (long)blockIdx.x * 256 + threadIdx.x;
  if (i >= n16) return;
  const int4* p = (const int4*)w + i * 4;
  int4 a = p[0], b = p[1], c = p[2], d = p[3];
  int4 o;
  o.x = (a.x & 255) | ((a.y & 255) << 8) | ((a.z & 255) << 16) | (a.w << 24);
  o.y = (b.x & 255) | ((b.y & 255) << 8) | ((b.z & 255) << 16) | (b.w << 24);
  o.z = (c.x & 255) | ((c.y & 255) << 8) | ((c.z & 255) << 16) | (c.w << 24);
  o.w = (d.x & 255) | ((d.y & 255) << 8) | ((d.z & 255) << 16) | (d.w << 24);
  ((int4*)wq)[i] = o;
}

__device__ __forceinline__ void gload_lds16(const void* g, void* l) {
  __builtin_amdgcn_global_load_lds((const __attribute__((address_space(1))) void*)g,
                                   (__attribute__((address_space(3))) void*)l,
                                   16, 0, 0);
}

// 256x256 tile, BK=64 i8, 8 waves (2M x 4N), per-wave 128x64 out, acc[8][4] i32.
// 64B logical rows paired into 128B phys rows, XOR ((pr&7)<<4) swizzle.
// Ledger: prologue stages tiles 0,1,2; iter t waits vmcnt(4) (tile t+1
// landed), stages tile t+3. Ring offsets constant-folded via x4 unroll.
__global__ __launch_bounds__(512, 2) void gemm256_i8_kernel(
    const unsigned char* __restrict__ A,   // [M,K] i8
    const unsigned char* __restrict__ Bw,  // [N,K] i8
    const float* __restrict__ sr,          // [M] per-row x scale
    const float* __restrict__ scale,
    const float* __restrict__ bias,
    float* __restrict__ C) {
  extern __shared__ char lds[];
  const int tid = threadIdx.x;
  const int lane = tid & 63;
  const int wid = tid >> 6;
  const int wm = wid >> 2;   // 0..1, rows wm*128
  const int wn = wid & 3;    // 0..3, cols wn*64
  const int l16 = lane & 15;
  const int kh = lane >> 4;  // 0..3

  // XCD-aware bijective swizzle (1376 % 8 == 0)
  const int bid = blockIdx.x;
  const int wg = (bid & 7) * (NBLK / 8) + (bid >> 3);
  const int tm = wg / NTN, tn = wg % NTN;
  const long m0 = (long)tm * BM, n0 = (long)tn * BN;

  // ---- staging source (pre-swizzled global addr; LDS dest linear) ----
  const int prl = tid >> 3;                          // phys row within 8KB issue
  const int cp = ((tid & 7) * 16) ^ ((prl & 7) << 4);
  const int hsel = cp >> 6;
  const int colb = cp & 63;
  const char* gA = (const char*)A + (m0 + 2 * prl + hsel) * (long)ROWB + colb;
  const char* gB = (const char*)Bw + (n0 + 2 * prl + hsel) * (long)ROWB + colb;
  const int ldsT = tid * 16;

  // ---- LDS read addressing (swizzled; logical row r -> phys r>>1, half r&1) ----
  const int inner = (((lane & 1) << 6) | (kh << 4)) ^ (((l16 >> 1) & 7) << 4);
  const int aB = (wm * 64 + (l16 >> 1)) * 128 + inner;           // + mi*1024
  const int bB = 16384 + (wn * 32 + (l16 >> 1)) * 128 + inner;   // + ni*1024

  i32x4 acc[8][4] = {};
  i32x4 afP[4], afN[4], bfA[4], bfB[4];

  // Stage for iter-position P (ring slot ((P+3)&3)), tile byte ktB + P*64.
#define STG_A(P, q) gload_lds16(gA + (q) * (128L * ROWB) + ktB + (P) * 64, \
                                lds + ((((P) + 3) & 3) * BUFB) + (q) * 8192 + ldsT)
#define STG_B(P, q) gload_lds16(gB + (q) * (128L * ROWB) + ktB + (P) * 64, \
                                lds + ((((P) + 3) & 3) * BUFB) + 16384 + (q) * 8192 + ldsT)

  // ---- prologue: stage K-tiles 0,1,2 into buffers 0,1,2 (static offsets) ----
  gload_lds16(gA, lds + ldsT);
  gload_lds16(gA + 128L * ROWB, lds + 8192 + ldsT);
  gload_lds16(gB, lds + 16384 + ldsT);
  gload_lds16(gB + 128L * ROWB, lds + 24576 + ldsT);
  gload_lds16(gA + 64, lds + BUFB + ldsT);
  gload_lds16(gA + 128L * ROWB + 64, lds + BUFB + 8192 + ldsT);
  gload_lds16(gB + 64, lds + BUFB + 16384 + ldsT);
  gload_lds16(gB + 128L * ROWB + 64, lds + BUFB + 24576 + ldsT);
  gload_lds16(gA + 128, lds + 2 * BUFB + ldsT);
  gload_lds16(gA + 128L * ROWB + 128, lds + 2 * BUFB + 8192 + ldsT);
  gload_lds16(gB + 128, lds + 2 * BUFB + 16384 + ldsT);
  gload_lds16(gB + 128L * ROWB + 128, lds + 2 * BUFB + 24576 + ldsT);
  asm volatile("s_waitcnt vmcnt(8)" ::: "memory");  // K-tile 0 landed (this wave)
  asm volatile("s_barrier" ::: "memory");           // all waves' tile-0 writes done
#pragma unroll
  for (int i = 0; i < 4; ++i) {
    afP[i] = *(const i32x4*)(lds + aB + i * 1024);   // A frags m0-3 of tile 0
    bfA[i] = *(const i32x4*)(lds + bB + i * 1024);
  }

  long ktB = 3 * 64;   // byte offset of tile staged at position P=0
  int t = 0;

  // ITER at ring position P (compile-time offsets). NO scheduling pins:
  // the compiler interleaves ds_reads with MFMAs and emits fine-grained
  // lgkmcnt. Barriers/vmcnt (memory clobber) still order memory ops.
#define ITER(P, BF_CUR, BF_NXT)                                               \
  {                                                                           \
    if (t < KT - 2) asm volatile("s_waitcnt vmcnt(4)" ::: "memory");          \
    else            asm volatile("s_waitcnt vmcnt(0)" ::: "memory");          \
    asm volatile("s_barrier" ::: "memory");                                   \
    if (t < KT - 3) { STG_A(P, 0); STG_A(P, 1); STG_B(P, 0); STG_B(P, 1); }   \
    _Pragma("unroll")                                                         \
    for (int i = 0; i < 4; ++i)                                               \
      afN[i] = *(const i32x4*)(lds + (P) * BUFB + aB + 4096 + i * 1024);      \
    _Pragma("unroll")                                                         \
    for (int mi = 0; mi < 4; ++mi)                                            \
      _Pragma("unroll")                                                       \
      for (int ni = 0; ni < 4; ++ni)                                          \
        acc[mi][ni] = __builtin_amdgcn_mfma_i32_16x16x64_i8(afP[mi], BF_CUR[ni], acc[mi][ni], 0, 0, 0); \
    if (t < KT - 1) {                                                         \
      _Pragma("unroll")                                                       \
      for (int i = 0; i < 4; ++i) {                                           \
        afP[i] = *(const i32x4*)(lds + (((P) + 1) & 3) * BUFB + aB + i * 1024); \
        BF_NXT[i] = *(const i32x4*)(lds + (((P) + 1) & 3) * BUFB + bB + i * 1024); \
      }                                                                       \
    }                                                                         \
    _Pragma("unroll")                                                         \
    for (int mi = 0; mi < 4; ++mi)                                            \
      _Pragma("unroll")                                                       \
      for (int ni = 0; ni < 4; ++ni)                                          \
        acc[4 + mi][ni] = __builtin_amdgcn_mfma_i32_16x16x64_i8(afN[mi], BF_CUR[ni], acc[4 + mi][ni], 0, 0, 0); \
    ++t;                                                                      \
  }

  for (int tt = 0; tt < KT / 4; ++tt) {
    ITER(0, bfA, bfB);
    ITER(1, bfB, bfA);
    ITER(2, bfA, bfB);
    ITER(3, bfB, bfA);
    ktB += 256;
  }
#undef ITER
#undef STG_A
#undef STG_B

  // ---- epilogue: y = i32acc * (sr[row]*s) + bias ----
  const float sw = scale[0];
  float bv[4];
#pragma unroll
  for (int ni = 0; ni < 4; ++ni) bv[ni] = bias[n0 + wn * 64 + ni * 16 + l16];
#pragma unroll
  for (int mi = 0; mi < 8; ++mi) {
#pragma unroll
    for (int j = 0; j < 4; ++j) {
      const long row = m0 + wm * 128 + mi * 16 + kh * 4 + j;
      const float rsw = sr[row] * sw;
#pragma unroll
      for (int ni = 0; ni < 4; ++ni) {
        const long col = n0 + wn * 64 + ni * 16 + l16;
        C[row * N_TOT + col] = (float)acc[mi][ni][j] * rsw + bv[ni];
      }
    }
  }
}

// ---- fallback (shouldn't trigger) ----
__global__ __launch_bounds__(256) void naive_kernel(const float* __restrict__ x,
                                                    const int* __restrict__ wq,
                                                    const float* __restrict__ scale,
                                                    const float* __restrict__ bias,
                                                    float* __restrict__ out) {
  long idx = (long)blockIdx.x * 256 + threadIdx.x;
  if (idx >= (long)M_TOT * N_TOT) return;
  long m = idx / N_TOT, n = idx % N_TOT;
  const float* xr = x + m * (long)K_TOT;
  const int* wr = wq + n * (long)K_TOT;
  float acc = 0.f;
  for (int k = 0; k < K_TOT; ++k) acc += xr[k] * (float)wr[k];
  out[idx] = acc * scale[0] + bias[n];
}

extern "C" void kernel_launch(void* const* d_in, const int* in_sizes, int n_in,
                              void* d_out, int out_size, void* d_ws, size_t ws_size,
                              hipStream_t stream) {
  const float* x = (const float*)d_in[0];
  const int* wq = (const int*)d_in[1];
  const float* scale = (const float*)d_in[2];
  const float* bias = (const float*)d_in[3];
  float* out = (float*)d_out;

  const long xe = (long)M_TOT * K_TOT;  // 33,554,432 B (i8)
  const long we = (long)N_TOT * K_TOT;  // 45,088,768 B (i8)
  const size_t need = (size_t)xe + we + M_TOT * sizeof(float);

  if (ws_size >= need) {
    char* xq = (char*)d_ws;
    char* wb = xq + xe;
    float* sr = (float*)(wb + we);
    quant_x_kernel<<<M_TOT, 256, 0, stream>>>(x, xq, sr);
    cvt_w8_kernel<<<(int)((we / 16 + 255) / 256), 256, 0, stream>>>(wq, wb, we / 16);
    (void)hipFuncSetAttribute((const void*)gemm256_i8_kernel,
                              hipFuncAttributeMaxDynamicSharedMemorySize, LDSB);
    gemm256_i8_kernel<<<NBLK, 512, LDSB, stream>>>((const unsigned char*)xq,
                                                   (const unsigned char*)wb,
                                                   sr, scale, bias, out);
  } else {
    long total = (long)M_TOT * N_TOT;
    naive_kernel<<<(int)((total + 255) / 256), 256, 0, stream>>>(x, wq, scale, bias, out);
  }
}